// Round 11
// baseline (754.546 us; speedup 1.0000x reference)
//
#include <hip/hip_runtime.h>
#include <hip/hip_bf16.h>

typedef unsigned int u32;
typedef unsigned long long u64;
typedef float v2f __attribute__((ext_vector_type(2)));
typedef float v4f __attribute__((ext_vector_type(4)));

// ---------------- workspace layout (bytes) ----------------
// conv phase: y + wT (wT aliases everything below, dead after k_conv1)
#define OFF_Y      0ull             // 8,388,608
#define OFF_WT     8388608ull       // 9,437,184 -> end 17,825,792 (= ws floor)
// post-conv phase (aliases wT region; all writers run after k_conv1):
#define OFF_SCORES 8388608ull       // 147,456 -> 8,536,064
#define OFF_DRAW   8536064ull       // 589,824 -> 9,125,888
#define OFF_TOPV   9125888ull       // 24,576 -> 9,150,464
#define OFF_BOXES  9150464ull       // 98,304 -> 9,248,768
#define OFF_VW     9248768ull       // 1,024 -> 9,249,792
#define OFF_HIST   9249792ull       // 131072 bins * 4 = 524,288 -> 9,774,080
#define OFF_MASK   9774080ull       // 6000*96*8 = 4,608,000 -> 14,382,080

#define NS     36864
#define PRE    6000
#define POST   300
#define SORTN  8192
#define MROW   96     // mask words per row (94 used)
#define HBINS  131072 // score histogram bins (sb>>13) — R1-R6 proven slack

// ====== K0: weight transpose gw[co][ci][k] -> wT[ci][k][co] (co fastest) ====
__global__ __launch_bounds__(256) void k_wtrans(const float* __restrict__ gw,
                                                float* __restrict__ wT) {
    int o = blockIdx.x * 256 + threadIdx.x;   // coalesced write
    if (o >= 512 * 512 * 9) return;
    int ci = o / 4608;
    int r = o - ci * 4608;
    int k = r >> 9;
    int co = r & 511;
    wT[o] = gw[co * 4608 + ci * 9 + k];
}

// ================= K1: 3x3 conv 512->512 + bias + relu (v6 — R6 green) ======
// grid 1024 = 16 co-blk x 64 h-blk -> 4 blocks/CU = 16 waves/CU.
// block 256 = 4 waves; tile 32 co x 1 row x 64 cols; wave = 8 co (pk pairs).
#define CI 16
#define XROW 66
#define CHUNK_ELEMS (CI * 3 * XROW)   // 3168
#define STAGE_IT 13
__global__ __launch_bounds__(256, 4) void k_conv1(const float* __restrict__ x,
                                                  const float* __restrict__ wT,
                                                  const float* __restrict__ gb,
                                                  float* __restrict__ y) {
    __shared__ float xs[CHUNK_ELEMS];   // 12,672 B
    const int t = threadIdx.x;
    const int tx = t & 63;
    const int wv = __builtin_amdgcn_readfirstlane(t >> 6);
    const int cob = (blockIdx.x & 15) << 5;
    const int h0 = blockIdx.x >> 4;
    const int co_base = cob + (wv << 3);   // 8 co per wave

    // staging map (constant across chunks; only ci-base shifts)
    int offs[STAGE_IT];
    u32 vmask = 0;
#pragma unroll
    for (int u = 0; u < STAGE_IT; ++u) {
        int idx = t + u * 256;
        offs[u] = 0;
        if (idx < CHUNK_ELEMS) {
            int ci = idx / (3 * XROW);
            int rem = idx - ci * (3 * XROW);
            int row = rem / XROW;
            int col = rem - row * XROW;
            int gr = h0 + row - 1, gc = col - 1;
            if ((unsigned)gr < 64u && (unsigned)gc < 64u) {
                offs[u] = ci * 4096 + (gr << 6) + gc;
                vmask |= 1u << u;
            }
        }
    }

    v2f acc2[4];
#pragma unroll
    for (int j = 0; j < 4; ++j) acc2[j] = (v2f){0.f, 0.f};

    float st[STAGE_IT];
#pragma unroll
    for (int u = 0; u < STAGE_IT; ++u)
        st[u] = (vmask >> u & 1) ? x[offs[u]] : 0.f;

#pragma unroll 1
    for (int cc = 0; cc < 32; ++cc) {
        if (cc) __syncthreads();
#pragma unroll
        for (int u = 0; u < STAGE_IT; ++u) {
            int idx = t + u * 256;
            if (idx < CHUNK_ELEMS) xs[idx] = st[u];
        }
        __syncthreads();
        if (cc + 1 < 32) {
            const float* xsrc = x + (cc + 1) * CI * 4096;
#pragma unroll
            for (int u = 0; u < STAGE_IT; ++u)
                st[u] = (vmask >> u & 1) ? xsrc[offs[u]] : 0.f;
        }

        const int cig0 = cc * CI;
#pragma unroll 2
        for (int ci = 0; ci < CI; ++ci) {
            float xr[9];
            {
                const float* xp = xs + ci * (3 * XROW) + tx;
#pragma unroll
                for (int r = 0; r < 3; ++r) {
                    xr[r * 3 + 0] = xp[r * XROW + 0];
                    xr[r * 3 + 1] = xp[r * XROW + 1];
                    xr[r * 3 + 2] = xp[r * XROW + 2];
                }
            }
            // wT[ci][k][co]: wave's 8 co contiguous -> 2 float4 per k
            const float* wk = wT + (size_t)(cig0 + ci) * 4608 + co_base;
#pragma unroll
            for (int k = 0; k < 9; ++k) {
                v4f wa = *(const v4f*)(wk + k * 512);
                v4f wb = *(const v4f*)(wk + k * 512 + 4);
                float xv = xr[k];
                v2f xp2 = {xv, xv};
                acc2[0] = __builtin_elementwise_fma(__builtin_shufflevector(wa, wa, 0, 1), xp2, acc2[0]);
                acc2[1] = __builtin_elementwise_fma(__builtin_shufflevector(wa, wa, 2, 3), xp2, acc2[1]);
                acc2[2] = __builtin_elementwise_fma(__builtin_shufflevector(wb, wb, 0, 1), xp2, acc2[2]);
                acc2[3] = __builtin_elementwise_fma(__builtin_shufflevector(wb, wb, 2, 3), xp2, acc2[3]);
            }
        }
    }

#pragma unroll
    for (int j = 0; j < 4; ++j) {
        int co0 = co_base + 2 * j;
        float v0 = acc2[j].x + gb[co0];
        float v1 = acc2[j].y + gb[co0 + 1];
        v0 = v0 > 0.f ? v0 : 0.f;
        v1 = v1 > 0.f ? v1 : 0.f;
        y[co0 * 4096 + (h0 << 6) + tx] = v0;
        y[(co0 + 1) * 4096 + (h0 << 6) + tx] = v1;
    }
}

// ================= K2: 1x1 heads, full K + sigmoid + hist ===================
// grid 64 px-chunks; block 256 = 64 px x 4 wave-groups; 4 staging rounds of
// 128 ci (transposed ys -> b128 reads); weights float4 VMEM broadcast.
__global__ __launch_bounds__(256) void k_heads(const float* __restrict__ y,
                                               const float* __restrict__ cw,
                                               const float* __restrict__ cb,
                                               const float* __restrict__ bw,
                                               const float* __restrict__ bb,
                                               float* __restrict__ scores,
                                               float* __restrict__ draw,
                                               u32* __restrict__ hist) {
    __shared__ __align__(16) float ys[64][132];  // 33,792 B
    const int t = threadIdx.x;
    const int px = t & 63;
    const int gu = __builtin_amdgcn_readfirstlane(t >> 6);
    const int px0 = blockIdx.x << 6;
    const int nch = (gu == 0) ? 12 : 11;

    const float* wrow[12];
#pragma unroll
    for (int j = 0; j < 12; ++j) {
        int ch = gu + 4 * j;
        if (ch < 9) wrow[j] = cw + ch * 512;
        else if (ch < 45) wrow[j] = bw + (ch - 9) * 512;
        else wrow[j] = cw;
    }
    float acc[12];
#pragma unroll
    for (int j = 0; j < 12; ++j) acc[j] = 0.f;

#pragma unroll 1
    for (int q = 0; q < 4; ++q) {
        const int cib = q << 7;
        if (q) __syncthreads();
        for (int idx = t; idx < 128 * 64; idx += 256) {
            int ci = idx >> 6;
            int pp = idx & 63;
            ys[pp][ci] = y[(cib + ci) * 4096 + px0 + pp];
        }
        __syncthreads();
#pragma unroll 1
        for (int cq = 0; cq < 32; ++cq) {
            float4 yv = *(const float4*)&ys[px][cq << 2];
            float4 wv[12];
#pragma unroll
            for (int j = 0; j < 12; ++j)
                if (j < nch) wv[j] = *(const float4*)(wrow[j] + cib + (cq << 2));
#pragma unroll
            for (int j = 0; j < 12; ++j)
                if (j < nch)
                    acc[j] += wv[j].x * yv.x + wv[j].y * yv.y + wv[j].z * yv.z + wv[j].w * yv.w;
        }
    }
    for (int j = 0; j < nch; ++j) {
        int ch = gu + 4 * j;
        int sp = px0 + px;
        if (ch < 9) {
            float z = acc[j] + cb[ch];
            float s = 1.f / (1.f + expf(-z));
            scores[(ch << 12) + sp] = s;
            u32 sb = __float_as_uint(s);
            atomicAdd(&hist[sb >> 13], 1u);
        } else {
            draw[((ch - 9) << 12) + sp] = acc[j] + bb[ch - 9];
        }
    }
}

// ======== K3: fused select = hist-scan + compact + bitonic sort + decode ====
__global__ __launch_bounds__(1024) void k_select(const u32* __restrict__ hist,
                                                 const float* __restrict__ scores,
                                                 const float* __restrict__ draw,
                                                 const float* __restrict__ anchors,
                                                 const int* __restrict__ ishape,
                                                 float* __restrict__ boxes,
                                                 float* __restrict__ topv,
                                                 u64* __restrict__ vw) {
    __shared__ u32 csum[1024];
    __shared__ u32 suf[1024];
    __shared__ u64 sk[SORTN];   // 64 KB
    __shared__ int sel_s, cnt_s;
    const int t = threadIdx.x;

    // suffix-scan of 131072-bin histogram -> boundary bin (rank 6000 from top)
    u32 s = 0;
    const u32* hp = hist + t * 128;
    for (int i = 0; i < 128; ++i) s += hp[i];
    csum[t] = s;
    suf[t] = s;
    if (t == 0) cnt_s = 0;
    __syncthreads();
    for (int off = 1; off < 1024; off <<= 1) {
        u32 v = suf[t] + ((t + off < 1024) ? suf[t + off] : 0u);
        __syncthreads();
        suf[t] = v;
        __syncthreads();
    }
    u32 above = suf[t] - csum[t];
    if (above < (u32)PRE && suf[t] >= (u32)PRE) {
        u32 run = above;
        int bstar = t * 128;
        u32 found = 0;
        for (int b2 = 127; b2 >= 0; --b2) {
            u32 c = hp[b2];
            if (!found && run + c >= (u32)PRE) { bstar = t * 128 + b2; found = 1; }
            if (!found) run += c;
        }
        sel_s = bstar;
    }
    for (int i = t; i < SORTN; i += 1024) sk[i] = 0;
    __syncthreads();

    // compact candidates into LDS
    const int sel = sel_s;
    for (int i = t; i < NS; i += 1024) {
        u32 sb = __float_as_uint(scores[i]);
        if ((int)(sb >> 13) >= sel) {
            int p = atomicAdd(&cnt_s, 1);
            if (p < SORTN) sk[p] = ((u64)sb << 32) | (u32)(~i);
        }
    }
    __syncthreads();

    // bitonic sort 8192 descending; j<=4 stages in registers
    const int base = t << 3;
    u64 a[8];
    {
#pragma unroll
        for (int u = 0; u < 8; ++u) a[u] = sk[base + u];
#pragma unroll
        for (int k = 2; k <= 8; k <<= 1) {
#pragma unroll
            for (int j = k >> 1; j > 0; j >>= 1) {
#pragma unroll
                for (int u = 0; u < 8; ++u) {
                    if ((u & j) == 0) {
                        int l = u | j;
                        bool up = (((base + u) & k) == 0);
                        u64 x0 = a[u], x1 = a[l];
                        if (up ? (x0 < x1) : (x0 > x1)) { a[u] = x1; a[l] = x0; }
                    }
                }
            }
        }
#pragma unroll
        for (int u = 0; u < 8; ++u) sk[base + u] = a[u];
        __syncthreads();
    }
    for (int k = 16; k <= SORTN; k <<= 1) {
        for (int j = k >> 1; j >= 8; j >>= 1) {
#pragma unroll
            for (int s2 = 0; s2 < 4; ++s2) {
                int pidx = t + (s2 << 10);
                int i = ((pidx & ~(j - 1)) << 1) | (pidx & (j - 1));
                int l = i | j;
                u64 x0 = sk[i], x1 = sk[l];
                bool up = ((i & k) == 0);
                if (up ? (x0 < x1) : (x0 > x1)) { sk[i] = x1; sk[l] = x0; }
            }
            __syncthreads();
        }
#pragma unroll
        for (int u = 0; u < 8; ++u) a[u] = sk[base + u];
        {
            bool up = ((base & k) == 0);
#pragma unroll
            for (int j = 4; j > 0; j >>= 1) {
#pragma unroll
                for (int u = 0; u < 8; ++u) {
                    if ((u & j) == 0) {
                        int l = u | j;
                        u64 x0 = a[u], x1 = a[l];
                        if (up ? (x0 < x1) : (x0 > x1)) { a[u] = x1; a[l] = x0; }
                    }
                }
            }
        }
#pragma unroll
        for (int u = 0; u < 8; ++u) sk[base + u] = a[u];
        __syncthreads();
    }

    // decode + clip + valid ballot
    const float wimg = (float)ishape[1], himg = (float)ishape[0];
#pragma unroll 1
    for (int s2 = 0; s2 < 6; ++s2) {
        int r = (s2 << 10) + t;
        bool valid = false;
        if (r < PRE) {
            u64 key = sk[r];
            u32 sb = (u32)(key >> 32);
            int i = (int)(~(u32)key);
            topv[r] = __uint_as_float(sb);
            int c = i >> 10;
            int t4 = i & 1023;
            float4 d4 = *(const float4*)(draw + c * 4096 + (t4 << 2));
            float4 a4 = *(const float4*)(anchors + i * 4);
            float aw = a4.z - a4.x, ah = a4.w - a4.y;
            float ax = a4.x + 0.5f * aw, ay = a4.y + 0.5f * ah;
            const float CLIPV = (float)4.135166556742356;
            float dw = fminf(d4.z, CLIPV);
            float dh = fminf(d4.w, CLIPV);
            float px = d4.x * aw + ax, py = d4.y * ah + ay;
            float pw = expf(dw) * aw, ph = expf(dh) * ah;
            float x1 = fminf(fmaxf(px - 0.5f * pw, 0.f), wimg);
            float y1 = fminf(fmaxf(py - 0.5f * ph, 0.f), himg);
            float x2 = fminf(fmaxf(px + 0.5f * pw, 0.f), wimg);
            float y2 = fminf(fmaxf(py + 0.5f * ph, 0.f), himg);
            valid = (x2 - x1 >= 16.f) && (y2 - y1 >= 16.f);
            *(float4*)(boxes + r * 4) = make_float4(x1, y1, x2, y2);
        }
        u64 bm = __ballot(valid);
        if ((t & 63) == 0) vw[(s2 << 4) + (t >> 6)] = bm;
    }
}

// ================= K4: suppression bitmask (iou > 0.7, j > row) =============
__global__ __launch_bounds__(256) void k_mask(const float* __restrict__ boxes,
                                              u64* __restrict__ mask) {
    __shared__ float4 cbx[16 * 65];
    const int t = threadIdx.x;
    const int r0 = blockIdx.x << 4;
    const int row = r0 + (t >> 4);
    const int wloc = t & 15;
    float4 rb = *(const float4*)(boxes + row * 4);
    float area_a = (rb.z - rb.x) * (rb.w - rb.y);
    for (int chunk = 0; chunk < 6; ++chunk) {
        int j0c = chunk << 10;
        for (int idx = t; idx < 1024; idx += 256) {
            int j = j0c + idx;
            float4 v = make_float4(0.f, 0.f, 0.f, 0.f);
            if (j < PRE) v = *(const float4*)(boxes + j * 4);
            cbx[(idx >> 6) * 65 + (idx & 63)] = v;
        }
        __syncthreads();
        u64 bits = 0;
        const float4* cbr = cbx + wloc * 65;
        for (int b = 0; b < 64; ++b) {
            int j = j0c + (wloc << 6) + b;
            float4 ob = cbr[b];
            float area_b = (ob.z - ob.x) * (ob.w - ob.y);
            float ltx = fmaxf(rb.x, ob.x), lty = fmaxf(rb.y, ob.y);
            float rbx = fminf(rb.z, ob.z), rby = fminf(rb.w, ob.w);
            float wx = fmaxf(rbx - ltx, 0.f), wy = fmaxf(rby - lty, 0.f);
            float inter = wx * wy;
            float uni = area_a + area_b - inter;
            float iou = (uni > 0.f) ? (inter / uni) : 0.f;
            if (iou > 0.7f && j > row && j < PRE) bits |= (1ull << b);
        }
        mask[(size_t)row * MROW + (chunk << 4) + wloc] = bits;
        __syncthreads();
    }
}

// ======== K5: fused NMS (serial greedy, batch-16 prefetch) + output write ===
__global__ __launch_bounds__(320) void k_nms_out(const u64* __restrict__ mask,
                                                 const u64* __restrict__ vw,
                                                 const float* __restrict__ boxes,
                                                 const float* __restrict__ topv,
                                                 float* __restrict__ out) {
    __shared__ u64 rem[MROW];
    __shared__ u64 rows16[16][MROW];   // 12,288 B
    __shared__ u64 kws[MROW];
    __shared__ int keepl[POST];
    const int tid = threadIdx.x;
    for (int i = tid; i < MROW; i += 320) { rem[i] = 0ull; kws[i] = 0ull; }
    __syncthreads();
    int kc = 0;
    bool done = false;
    for (int w = 0; w < 94 && !done; ++w) {
        u64 aw = vw[w] & ~rem[w];
        u64 kwbits = 0;
        while (aw != 0ull && !done) {
            int bq[16];
            u64 tmp = aw;
#pragma unroll
            for (int q2 = 0; q2 < 16; ++q2) {
                bq[q2] = tmp ? __builtin_ctzll(tmp) : 64;
                tmp &= tmp - 1;
            }
#pragma unroll
            for (int u = 0; u < 5; ++u) {
                int i = tid + u * 320;
                if (i < 16 * MROW) {
                    int q2 = i / MROW;
                    int ww = i - q2 * MROW;
                    if (bq[q2] < 64)
                        rows16[q2][ww] = mask[(size_t)((w << 6) + bq[q2]) * MROW + ww];
                }
            }
            __syncthreads();
            for (int q2 = 0; q2 < 16; ++q2) {
                int b = bq[q2];
                if (b >= 64) break;
                if (!((aw >> b) & 1ull)) continue;
                if (tid == 0) keepl[kc] = (w << 6) + b;
                kc++;
                kwbits |= (1ull << b);
                if (kc >= POST) { done = true; break; }
                if (tid < MROW) rem[tid] |= rows16[q2][tid];
                aw &= ~rows16[q2][w];
                aw &= ~(1ull << b);
            }
            __syncthreads();
        }
        if (tid == 0) kws[w] = kwbits;
        __syncthreads();
    }
    __syncthreads();

    int j = tid;
    if (j >= POST) return;
    int r;
    float sc;
    if (j < kc) {
        r = keepl[j];
        sc = topv[r];
    } else {
        int target = j - kc;
        r = PRE - 1;
        int cum = 0;
        for (int w = 0; w < 94; ++w) {
            u64 kb = kws[w];
            int nvalid = (w < 93) ? 64 : 48;
            u64 vmask2 = (nvalid == 64) ? ~0ull : ((1ull << nvalid) - 1ull);
            u64 nk = (~kb) & vmask2;
            int c = __popcll(nk);
            if (cum + c > target) {
                int need = target - cum;
                u64 m = nk;
                for (int q = 0; q < need; ++q) m &= (m - 1);
                r = (w << 6) + __builtin_ctzll(m);
                break;
            }
            cum += c;
        }
        sc = -1.0f;
    }
    out[j * 4 + 0] = boxes[r * 4 + 0];
    out[j * 4 + 1] = boxes[r * 4 + 1];
    out[j * 4 + 2] = boxes[r * 4 + 2];
    out[j * 4 + 3] = boxes[r * 4 + 3];
    out[1200 + j] = sc;
}

extern "C" void kernel_launch(void* const* d_in, const int* in_sizes, int n_in,
                              void* d_out, int out_size, void* d_ws, size_t ws_size,
                              hipStream_t stream) {
    const float* x = (const float*)d_in[0];
    const float* anchors = (const float*)d_in[1];
    const int* ishape = (const int*)d_in[2];
    const float* c1w = (const float*)d_in[3];
    const float* c1b = (const float*)d_in[4];
    const float* clw = (const float*)d_in[5];
    const float* clb = (const float*)d_in[6];
    const float* bxw = (const float*)d_in[7];
    const float* bxb = (const float*)d_in[8];

    char* ws = (char*)d_ws;
    float* y      = (float*)(ws + OFF_Y);
    float* wT     = (float*)(ws + OFF_WT);
    float* scores = (float*)(ws + OFF_SCORES);
    float* draw   = (float*)(ws + OFF_DRAW);
    u32*   hist   = (u32*)(ws + OFF_HIST);
    float* topv   = (float*)(ws + OFF_TOPV);
    float* boxes  = (float*)(ws + OFF_BOXES);
    u64*   vw     = (u64*)(ws + OFF_VW);
    u64*   mask   = (u64*)(ws + OFF_MASK);

    k_wtrans<<<(512 * 512 * 9 + 255) / 256, 256, 0, stream>>>(c1w, wT);
    k_conv1<<<1024, 256, 0, stream>>>(x, wT, c1b, y);
    // hist aliases wT -> zero only after conv consumed wT
    (void)hipMemsetAsync(hist, 0, HBINS * sizeof(u32), stream);
    k_heads<<<64, 256, 0, stream>>>(y, clw, clb, bxw, bxb, scores, draw, hist);
    k_select<<<1, 1024, 0, stream>>>(hist, scores, draw, anchors, ishape, boxes, topv, vw);
    k_mask<<<PRE / 16, 256, 0, stream>>>(boxes, mask);
    k_nms_out<<<1, 320, 0, stream>>>(mask, vw, boxes, topv, (float*)d_out);
}